// Round 6
// baseline (632.270 us; speedup 1.0000x reference)
//
#include <hip/hip_runtime.h>
#include <hip/hip_bf16.h>
#include <hip/hip_cooperative_groups.h>

// TVHMM forward log-likelihood, chunk-parallel linear-domain operator scan.
// R6: 3 launches (was 8): k_emis(+prep fused), k_trans (full-line coalesced
//     stores), cooperative k_scanall (scan tree + final with grid.sync).
// ws layout (bytes), ~73.5 MB total:
//   0x0000000 emp[8192][64] f32   0x0200000 cvec[8192] f32
//   0x0220000 sc1[1024][4]  0x0224000 sc2[128][4]  0x0225000 sc3[16][4]
//   0x0226000 sc4[1][4]
//   0x0240000 Xsw[8192][128] bf16 pre-swizzled (2 MB)
//   0x0440000 Wsw[64*64][128] bf16 pre-swizzled (1 MB)
//   0x0600000 Ap[8192][64][64] bf16 (64 MB), scan tree folds in place

namespace cg = cooperative_groups;

typedef unsigned int u32;
typedef unsigned short u16;

#define T_LEN 8192

typedef __attribute__((ext_vector_type(8))) short bf16x8;
typedef __attribute__((ext_vector_type(4))) float f32x4;

__device__ __forceinline__ float bflo(u32 u){ return __uint_as_float(u << 16); }
__device__ __forceinline__ float bfhi(u32 u){ return __uint_as_float(u & 0xffff0000u); }
__device__ __forceinline__ u32 f2bf(float x){
  u32 b = __float_as_uint(x);
  return (b + 0x7fffu + ((b >> 16) & 1u)) >> 16;
}
__device__ __forceinline__ u32 pack2bf(float a, float b){
  return f2bf(a) | (f2bf(b) << 16);
}

__device__ __forceinline__ void gld_lds16(const void* g, void* l){
#if defined(__has_builtin) && __has_builtin(__builtin_amdgcn_global_load_lds)
  __builtin_amdgcn_global_load_lds(
      (const __attribute__((address_space(1))) unsigned int*)g,
      (__attribute__((address_space(3))) unsigned int*)l, 16, 0, 0);
#else
  *(uint4*)((char*)l + (threadIdx.x & 63) * 16) = *(const uint4*)g;
#endif
}

// ---------------------------------------------------------------- k_emis
// emissions (mu / exp(-lv) staged in padded LDS; logdet per lane) + fused
// f32->bf16 pre-swizzled casts of X and W for k_trans's global_load_lds.
__global__ __launch_bounds__(256) void k_emis(
    const float* __restrict__ Y, const float* __restrict__ mu,
    const float* __restrict__ lvu,
    const float* __restrict__ X, const float* __restrict__ W,
    float* __restrict__ emp, float* __restrict__ cvec,
    u16* __restrict__ Xsw, u16* __restrict__ Wsw)
{
  __shared__ float muT_s[64][65];   // [d][k], +1 pad
  __shared__ float ivT_s[64][65];   // lv then exp(-lv)
  const int tid = threadIdx.x;
  const int w = tid >> 6, k = tid & 63;

  #pragma unroll
  for (int u = 0; u < 4; ++u){      // stage mu, clipped lv (transposed)
    int f4 = u*256 + tid;
    int r = f4 >> 4, c4 = (f4 & 15) * 4;
    float4 m4 = *(const float4*)(mu + (size_t)f4*4);
    float4 l4 = *(const float4*)(lvu + (size_t)f4*4);
    muT_s[c4+0][r] = m4.x; muT_s[c4+1][r] = m4.y;
    muT_s[c4+2][r] = m4.z; muT_s[c4+3][r] = m4.w;
    ivT_s[c4+0][r] = fminf(fmaxf(l4.x, -6.f), 6.f);
    ivT_s[c4+1][r] = fminf(fmaxf(l4.y, -6.f), 6.f);
    ivT_s[c4+2][r] = fminf(fmaxf(l4.z, -6.f), 6.f);
    ivT_s[c4+3][r] = fminf(fmaxf(l4.w, -6.f), 6.f);
  }
  __syncthreads();
  float ld = 0.f;
  #pragma unroll 8
  for (int d = 0; d < 64; ++d) ld += ivT_s[d][k];   // logdet[k]
  __syncthreads();
  if (w == 0){
    #pragma unroll 8
    for (int d = 0; d < 64; ++d) ivT_s[d][k] = __expf(-ivT_s[d][k]);
  }
  __syncthreads();

  const int t = blockIdx.x * 4 + w;
  float y = Y[(size_t)t*64 + k];
  float quad = 0.f;
  #pragma unroll 8
  for (int d = 0; d < 64; ++d){
    float yd = __shfl(y, d, 64);
    float df = yd - muT_s[d][k];
    quad = fmaf(df*df, ivT_s[d][k], quad);
  }
  float le = -0.5f*(117.6241322f + ld + quad);   // 64*log(2pi)
  float m = le;
  #pragma unroll
  for (int off = 1; off < 64; off <<= 1) m = fmaxf(m, __shfl_xor(m, off, 64));
  emp[(size_t)t*64 + k] = __expf(le - m);
  if (k == 0) cvec[t] = m;

  // X cast: this block's 4 t-rows = 128 float4 (swizzled for linear gld_lds)
  if (tid < 128){
    int rl = tid >> 5, c32 = tid & 31;
    int tr = blockIdx.x*4 + rl;
    float4 v = *(const float4*)(X + (size_t)tr*128 + c32*4);
    int c16 = c32 >> 1, h = c32 & 1;
    int byte = tr*256 + ((c16 ^ (tr & 7))*16 + h*8);
    *(uint2*)((char*)Xsw + byte) = make_uint2(pack2bf(v.x,v.y), pack2bf(v.z,v.w));
  }
  // W cast: blocks 0..511, 256 float4 each
  if (blockIdx.x < 512){
    int f4 = blockIdx.x*256 + tid;
    int r = f4 >> 5, c32 = f4 & 31;    // r = i*64+j
    float4 v = *(const float4*)(W + (size_t)f4*4);
    int c16 = c32 >> 1, h = c32 & 1;
    int byte = r*256 + ((c16 ^ (r & 7))*16 + h*8);
    *(uint2*)((char*)Wsw + byte) = make_uint2(pack2bf(v.x,v.y), pack2bf(v.z,v.w));
  }
}

// ---------------------------------------------------------------- k_trans (MFMA)
// Block (bt, ip): 64 t-rows x 2 source states i. C^T compute (M=j, N=t);
// exp (logits ~ +-2, no max-sub), j-sum via 2 shfl, normalization in copy-out.
// Copy-out: every store instruction covers 4 rows x 256B fully (no partial
// HBM sectors).
__global__ __launch_bounds__(256) void k_trans(
    const u16* __restrict__ Xsw, const u16* __restrict__ Wsw,
    const float* __restrict__ bmat, const float* __restrict__ emp,
    u16* __restrict__ Ap)
{
  __shared__ __align__(16) u16 Wt[128*128];   // 32 KB (2 i-slices, swizzled)
  __shared__ __align__(16) u16 Xt[64*128];    // 16 KB; reused as Ct
  __shared__ float Sred[8][64];               // 2 KB
  const int tid = threadIdx.x;
  const int lane = tid & 63, w = tid >> 6;
  const int lr = lane & 15, lg = lane >> 4;
  const int t0 = blockIdx.x * 64;
  const int i0 = blockIdx.y * 2;

  {
    const char* xsrc = (const char*)(Xsw + (size_t)t0*128);
    const char* wsrc = (const char*)(Wsw + (size_t)i0*64*128);
    #pragma unroll
    for (int c = 0; c < 4; ++c){
      int kb = w*4 + c;
      gld_lds16(xsrc + kb*1024 + lane*16, (char*)Xt + kb*1024);
    }
    #pragma unroll
    for (int c = 0; c < 8; ++c){
      int kb = w*8 + c;
      gld_lds16(wsrc + kb*1024 + lane*16, (char*)Wt + kb*1024);
    }
  }
  __syncthreads();

  f32x4 acc[2][4] = {};
  #pragma unroll
  for (int kg = 0; kg < 4; ++kg){
    const int kc = kg*4 + lg;
    bf16x8 a[2], b[4];
    #pragma unroll
    for (int jt = 0; jt < 2; ++jt){
      int row = (w + jt*4)*16 + lr;     // Wt row = i_local*64 + j
      a[jt] = *(const bf16x8*)((const char*)Wt + row*256 + ((kc ^ (row & 7))*16));
    }
    #pragma unroll
    for (int tt = 0; tt < 4; ++tt){
      int row = tt*16 + lr;             // Xt row = t local
      b[tt] = *(const bf16x8*)((const char*)Xt + row*256 + ((kc ^ (row & 7))*16));
    }
    #pragma unroll
    for (int jt = 0; jt < 2; ++jt)
      #pragma unroll
      for (int tt = 0; tt < 4; ++tt)
        acc[jt][tt] = __builtin_amdgcn_mfma_f32_16x16x32_bf16(a[jt], b[tt], acc[jt][tt], 0, 0, 0);
  }

  float bvv[2][4];
  #pragma unroll
  for (int jt = 0; jt < 2; ++jt){
    int q = w + jt*4;
    int ig = i0 + (q >> 2);
    #pragma unroll
    for (int reg = 0; reg < 4; ++reg)
      bvv[jt][reg] = bmat[ig*64 + (q & 3)*16 + lg*4 + reg];
  }

  __syncthreads();
  u16* Ct = Xt;                         // [64 t][128 j] bf16, row-swizzled

  #pragma unroll
  for (int jt = 0; jt < 2; ++jt){
    const int q = w + jt*4;
    #pragma unroll
    for (int tt = 0; tt < 4; ++tt){
      const int t = tt*16 + lr;
      float e0 = __expf(acc[jt][tt][0] + bvv[jt][0]);
      float e1 = __expf(acc[jt][tt][1] + bvv[jt][1]);
      float e2 = __expf(acc[jt][tt][2] + bvv[jt][2]);
      float e3 = __expf(acc[jt][tt][3] + bvv[jt][3]);
      float s = e0 + e1 + e2 + e3;
      s += __shfl_xor(s, 16, 64);
      s += __shfl_xor(s, 32, 64);
      if (lg == 0) Sred[q][t] = s;
      const int byte = t*256 + ((q*32 + lg*8) ^ ((t & 7) << 4));
      *(u32*)((char*)Ct + byte)     = pack2bf(e0, e1);
      *(u32*)((char*)Ct + byte + 4) = pack2bf(e2, e3);
    }
  }
  __syncthreads();

  { // copy-out: wave w owns rows w*16..w*16+15; per u, 4 rows x 256B full
    const int rl = lane >> 4;           // row in quad
    const int ch = lane & 15;           // 16B chunk in 256B row
    const int h = ch >> 3;              // i-half
    #pragma unroll
    for (int u = 0; u < 4; ++u){
      const int row = w*16 + u*4 + rl;
      float s = Sred[h*4+0][row] + Sred[h*4+1][row]
              + Sred[h*4+2][row] + Sred[h*4+3][row];
      const float inv = 1.0f / s;
      uint4 v = *(const uint4*)((const char*)Ct + row*256 + ((ch*16) ^ ((row & 7) << 4)));
      const float* er = emp + (size_t)(t0 + row)*64 + (ch & 7)*8;
      float4 ea = *(const float4*)(er);
      float4 eb = *(const float4*)(er + 4);
      u32 r0 = pack2bf(bflo(v.x)*inv*ea.x, bfhi(v.x)*inv*ea.y);
      u32 r1 = pack2bf(bflo(v.y)*inv*ea.z, bfhi(v.y)*inv*ea.w);
      u32 r2 = pack2bf(bflo(v.z)*inv*eb.x, bfhi(v.z)*inv*eb.y);
      u32 r3 = pack2bf(bflo(v.w)*inv*eb.z, bfhi(v.w)*inv*eb.w);
      *(uint4*)(Ap + (size_t)(t0 + row)*4096 + (size_t)i0*64 + ch*8) = make_uint4(r0, r1, r2, r3);
    }
  }
}

// ---------------------------------------------------------------- fold_chunk
// Fold cnt matrices (slot c*mstride, 4096 elems each) into one, in place at
// slot c0_in*mstride. Transposed-space MFMA (verified R4/R5).
__device__ void fold_chunk(
    u16* mats, int c0_in, int mstride, int cnt_in, int skip,
    const float* in_sc, float* out_sc, int tid, u32 (&Apk)[2][32*68])
{
  const int lane = tid & 63, w = tid >> 6;
  const int r16 = lane & 15, oct = lane >> 4;
  int c0 = c0_in + skip, cnt = cnt_in - skip;
  const size_t out_slot = (size_t)c0_in * mstride;

  bf16x8 Bf[2];
  {
    const u16* m0 = mats + ((size_t)c0*mstride << 12) + (w*16 + r16)*64 + oct*8;
    Bf[0] = *(const bf16x8*)(m0);
    Bf[1] = *(const bf16x8*)(m0 + 32);
  }
  float S = in_sc ? in_sc[c0*4 + w] : 0.0f;

  const int lp = tid >> 3, c8 = tid & 7;
  auto STAGE = [&](int buf, const u16* src){
    const uint4 A = *(const uint4*)(src + lp*128 + c8*8);
    const uint4 B = *(const uint4*)(src + lp*128 + 64 + c8*8);
    uint4 o0, o1;
    o0.x = (A.x & 0xffffu) | (B.x << 16);
    o0.y = (A.x >> 16)     | (B.x & 0xffff0000u);
    o0.z = (A.y & 0xffffu) | (B.y << 16);
    o0.w = (A.y >> 16)     | (B.y & 0xffff0000u);
    o1.x = (A.z & 0xffffu) | (B.z << 16);
    o1.y = (A.z >> 16)     | (B.z & 0xffff0000u);
    o1.z = (A.w & 0xffffu) | (B.w << 16);
    o1.w = (A.w >> 16)     | (B.w & 0xffff0000u);
    u32* dst = &Apk[buf][lp*68 + c8*8];
    *(uint4*)(dst)     = o0;
    *(uint4*)(dst + 4) = o1;
  };

  if (cnt > 1) STAGE(0, mats + ((size_t)(c0+1)*mstride << 12));
  __syncthreads();
  int cur = 0;
  for (int kk = 1; kk < cnt; ++kk){
    if (kk + 1 < cnt) STAGE(cur ^ 1, mats + ((size_t)(c0 + kk + 1)*mstride << 12));

    if (in_sc){
      const float* sp = in_sc + (size_t)(c0 + kk)*4;
      float s0=sp[0], s1=sp[1], s2=sp[2], s3=sp[3];
      float sm = fmaxf(fmaxf(s0,s1), fmaxf(s2,s3));
      S += sm;
      #pragma unroll
      for (int kt = 0; kt < 2; ++kt){
        float slo = (kt == 0) ? s0 : s2;
        float shi = (kt == 0) ? s1 : s3;
        float se = __expf(((oct >> 1) ? shi : slo) - sm);
        uint4 bv4 = __builtin_bit_cast(uint4, Bf[kt]);
        bv4.x = pack2bf(bflo(bv4.x)*se, bfhi(bv4.x)*se);
        bv4.y = pack2bf(bflo(bv4.y)*se, bfhi(bv4.y)*se);
        bv4.z = pack2bf(bflo(bv4.z)*se, bfhi(bv4.z)*se);
        bv4.w = pack2bf(bflo(bv4.w)*se, bfhi(bv4.w)*se);
        Bf[kt] = __builtin_bit_cast(bf16x8, bv4);
      }
    }

    f32x4 acc[4] = {};
    const u32* Ab = &Apk[cur][0];
    #pragma unroll
    for (int kt = 0; kt < 2; ++kt){
      const u32* gb = Ab + (kt*16 + oct*4)*68 + r16;
      #pragma unroll
      for (int jt = 0; jt < 4; ++jt){
        const u32* g = gb + jt*16;
        uint4 av = make_uint4(g[0], g[68], g[136], g[204]);
        acc[jt] = __builtin_amdgcn_mfma_f32_16x16x32_bf16(
            __builtin_bit_cast(bf16x8, av), Bf[kt], acc[jt], 0, 0, 0);
      }
    }

    float mx = acc[0][0];
    #pragma unroll
    for (int jt = 0; jt < 4; ++jt)
      #pragma unroll
      for (int q = 0; q < 4; ++q) mx = fmaxf(mx, acc[jt][q]);
    #pragma unroll
    for (int off = 1; off < 64; off <<= 1) mx = fmaxf(mx, __shfl_xor(mx, off, 64));
    float inv = 1.0f / mx;
    S += __logf(mx);

    u32 p0[4], p1[4];
    #pragma unroll
    for (int jt = 0; jt < 4; ++jt){
      p0[jt] = pack2bf(acc[jt][0]*inv, acc[jt][1]*inv);
      p1[jt] = pack2bf(acc[jt][2]*inv, acc[jt][3]*inv);
    }
    const int s0l = r16 + 32*(oct & 1), s1l = s0l + 16;
    const bool hi = (oct >> 1) != 0;
    #pragma unroll
    for (int kt = 0; kt < 2; ++kt){
      u32 a0 = __shfl(p0[2*kt],   s0l, 64), a1 = __shfl(p1[2*kt],   s0l, 64);
      u32 a2 = __shfl(p0[2*kt],   s1l, 64), a3 = __shfl(p1[2*kt],   s1l, 64);
      u32 b0 = __shfl(p0[2*kt+1], s0l, 64), b1 = __shfl(p1[2*kt+1], s0l, 64);
      u32 b2 = __shfl(p0[2*kt+1], s1l, 64), b3 = __shfl(p1[2*kt+1], s1l, 64);
      uint4 nb;
      nb.x = hi ? b0 : a0;
      nb.y = hi ? b1 : a1;
      nb.z = hi ? b2 : a2;
      nb.w = hi ? b3 : a3;
      Bf[kt] = __builtin_bit_cast(bf16x8, nb);
    }
    cur ^= 1;
    __syncthreads();
  }
  {
    u16* outp = mats + (out_slot << 12) + (w*16 + r16)*64 + oct*8;
    *(bf16x8*)(outp)      = Bf[0];
    *(bf16x8*)(outp + 32) = Bf[1];
    if (lane == 0) out_sc[w] = S;
  }
}

// ---------------------------------------------------------------- final_ll
__device__ void final_ll(
    const float* init_logits, const float* emp, const float* cvec,
    const u16* Mfin, const float* scfin, float* out, int tid)
{
  __shared__ float wsum[4];
  float part = 0.f;
  for (int t = tid; t < T_LEN; t += 256) part += cvec[t];
  #pragma unroll
  for (int off = 1; off < 64; off <<= 1) part += __shfl_xor(part, off, 64);
  if ((tid & 63) == 0) wsum[tid >> 6] = part;
  __syncthreads();
  if (tid >= 64) return;
  const float csum = wsum[0] + wsum[1] + wsum[2] + wsum[3];
  const int k = tid;
  float ilv = init_logits[k];
  float m = ilv;
  #pragma unroll
  for (int off = 1; off < 64; off <<= 1) m = fmaxf(m, __shfl_xor(m, off, 64));
  float e = __expf(ilv - m);
  float s = e;
  #pragma unroll
  for (int off = 1; off < 64; off <<= 1) s += __shfl_xor(s, off, 64);
  float alpha = (e / s) * emp[k];
  const float* sp = scfin;
  float sm = fmaxf(fmaxf(sp[0], sp[1]), fmaxf(sp[2], sp[3]));
  alpha *= __expf(sp[k >> 4] - sm);
  float S = sm;
  float an = 0.f;
  for (int i2 = 0; i2 < 64; ++i2){
    float av = __shfl(alpha, i2, 64);
    an = fmaf(av, __uint_as_float(((u32)Mfin[i2*64 + k]) << 16), an);
  }
  float tot = an;
  #pragma unroll
  for (int off = 1; off < 64; off <<= 1) tot += __shfl_xor(tot, off, 64);
  if (k == 0) out[0] = __logf(tot) + S + csum;
}

// ---------------------------------------------------------------- k_scanall
// Cooperative: full scan tree (1024x8 -> 128x8 -> 16x8 -> 1x16) + final.
__global__ __launch_bounds__(256, 4) void k_scanall(
    u16* mats, const float* init_logits, const float* emp, const float* cvec,
    float* sc1, float* sc2, float* sc3, float* sc4, float* out)
{
  __shared__ u32 Apk[2][32*68];
  cg::grid_group grid = cg::this_grid();
  const int b = blockIdx.x;
  const int tid = threadIdx.x;
  fold_chunk(mats, b*8, 1, 8, (b == 0) ? 1 : 0, nullptr, sc1 + b*4, tid, Apk);
  grid.sync();
  if (b < 128) fold_chunk(mats, b*8, 8, 8, 0, sc1, sc2 + b*4, tid, Apk);
  grid.sync();
  if (b < 16) fold_chunk(mats, b*8, 64, 8, 0, sc2, sc3 + b*4, tid, Apk);
  grid.sync();
  if (b == 0) fold_chunk(mats, 0, 512, 16, 0, sc3, sc4, tid, Apk);
  grid.sync();
  if (b == 0) final_ll(init_logits, emp, cvec, mats, sc4, out, tid);
}

// ---------------------------------------------------------------- fallback wrappers
__global__ __launch_bounds__(256) void k_scan_lvl(
    u16* mats, int mstride, int per_wg, int skip0,
    const float* __restrict__ in_sc, float* __restrict__ out_sc)
{
  __shared__ u32 Apk[2][32*68];
  const int b = blockIdx.x;
  fold_chunk(mats, b*per_wg, mstride, per_wg, (b == 0) ? skip0 : 0,
             in_sc, out_sc + b*4, threadIdx.x, Apk);
}

__global__ __launch_bounds__(256) void k_final_k(
    const float* __restrict__ init_logits, const float* __restrict__ emp,
    const float* __restrict__ cvec, const u16* __restrict__ Mfin,
    const float* __restrict__ scfin, float* __restrict__ out)
{
  final_ll(init_logits, emp, cvec, Mfin, scfin, out, threadIdx.x);
}

// ---------------------------------------------------------------- launch
extern "C" void kernel_launch(void* const* d_in, const int* in_sizes, int n_in,
                              void* d_out, int out_size, void* d_ws, size_t ws_size,
                              hipStream_t stream)
{
  const float* X  = (const float*)d_in[0];
  const float* Y  = (const float*)d_in[1];
  const float* il = (const float*)d_in[2];
  const float* W  = (const float*)d_in[3];
  const float* bm = (const float*)d_in[4];
  const float* mu = (const float*)d_in[5];
  const float* lv = (const float*)d_in[6];
  float* out = (float*)d_out;
  char* ws = (char*)d_ws;
  (void)in_sizes; (void)n_in; (void)out_size; (void)ws_size; // need ~73.5 MB ws

  float* emp  = (float*)(ws + 0x0000000);
  float* cvec = (float*)(ws + 0x0200000);
  float* sc1  = (float*)(ws + 0x0220000);
  float* sc2  = (float*)(ws + 0x0224000);
  float* sc3  = (float*)(ws + 0x0225000);
  float* sc4  = (float*)(ws + 0x0226000);
  u16*   Xsw  = (u16*)  (ws + 0x0240000);
  u16*   Wsw  = (u16*)  (ws + 0x0440000);
  u16*   Ap   = (u16*)  (ws + 0x0600000);

  k_emis <<<2048, 256, 0, stream>>>(Y, mu, lv, X, W, emp, cvec, Xsw, Wsw);
  k_trans<<<dim3(128, 32), 256, 0, stream>>>(Xsw, Wsw, bm, emp, Ap);

  void* args[] = {(void*)&Ap, (void*)&il, (void*)&emp, (void*)&cvec,
                  (void*)&sc1, (void*)&sc2, (void*)&sc3, (void*)&sc4, (void*)&out};
  hipError_t rc = hipLaunchCooperativeKernel((void*)k_scanall, dim3(1024), dim3(256),
                                             args, 0, stream);
  if (rc != hipSuccess){
    // deterministic fallback: separate launches (same math)
    k_scan_lvl<<<1024, 256, 0, stream>>>(Ap,   1,  8, 1, (const float*)nullptr, sc1);
    k_scan_lvl<<<128,  256, 0, stream>>>(Ap,   8,  8, 0, sc1, sc2);
    k_scan_lvl<<<16,   256, 0, stream>>>(Ap,  64,  8, 0, sc2, sc3);
    k_scan_lvl<<<1,    256, 0, stream>>>(Ap, 512, 16, 0, sc3, sc4);
    k_final_k <<<1,    256, 0, stream>>>(il, emp, cvec, Ap, sc4, out);
  }
}

// Round 7
// 191.097 us; speedup vs baseline: 3.3086x; 3.3086x over previous
//
#include <hip/hip_runtime.h>
#include <hip/hip_bf16.h>

// TVHMM forward log-likelihood, chunk-parallel linear-domain operator scan.
// R7: revert cooperative (grid.sync ~125us/sync on MI355X — measured R6).
//     6 launches: k_emis(+prep), k_trans (full-line stores, R6 fix kept),
//     scan L0 1024x8 / L1 128x8 / L2 16x8, k_tail (fold16->1 + final ll).
// ws layout (bytes), ~73.5 MB total:
//   0x0000000 emp[8192][64] f32   0x0200000 cvec[8192] f32
//   0x0220000 sc1[1024][4]  0x0224000 sc2[128][4]  0x0225000 sc3[16][4]
//   0x0240000 Xsw[8192][128] bf16 pre-swizzled (2 MB)
//   0x0440000 Wsw[64*64][128] bf16 pre-swizzled (1 MB)
//   0x0600000 Ap[8192][64][64] bf16 (64 MB), scan tree folds in place

typedef unsigned int u32;
typedef unsigned short u16;

#define T_LEN 8192

typedef __attribute__((ext_vector_type(8))) short bf16x8;
typedef __attribute__((ext_vector_type(4))) float f32x4;

__device__ __forceinline__ float bflo(u32 u){ return __uint_as_float(u << 16); }
__device__ __forceinline__ float bfhi(u32 u){ return __uint_as_float(u & 0xffff0000u); }
__device__ __forceinline__ u32 f2bf(float x){
  u32 b = __float_as_uint(x);
  return (b + 0x7fffu + ((b >> 16) & 1u)) >> 16;
}
__device__ __forceinline__ u32 pack2bf(float a, float b){
  return f2bf(a) | (f2bf(b) << 16);
}

__device__ __forceinline__ void gld_lds16(const void* g, void* l){
#if defined(__has_builtin) && __has_builtin(__builtin_amdgcn_global_load_lds)
  __builtin_amdgcn_global_load_lds(
      (const __attribute__((address_space(1))) unsigned int*)g,
      (__attribute__((address_space(3))) unsigned int*)l, 16, 0, 0);
#else
  *(uint4*)((char*)l + (threadIdx.x & 63) * 16) = *(const uint4*)g;
#endif
}

// ---------------------------------------------------------------- k_emis
// emissions (mu / exp(-lv) staged in padded LDS; logdet per lane) + fused
// f32->bf16 pre-swizzled casts of X and W for k_trans's global_load_lds.
__global__ __launch_bounds__(256) void k_emis(
    const float* __restrict__ Y, const float* __restrict__ mu,
    const float* __restrict__ lvu,
    const float* __restrict__ X, const float* __restrict__ W,
    float* __restrict__ emp, float* __restrict__ cvec,
    u16* __restrict__ Xsw, u16* __restrict__ Wsw)
{
  __shared__ float muT_s[64][65];   // [d][k], +1 pad
  __shared__ float ivT_s[64][65];   // lv then exp(-lv)
  const int tid = threadIdx.x;
  const int w = tid >> 6, k = tid & 63;

  #pragma unroll
  for (int u = 0; u < 4; ++u){      // stage mu, clipped lv (transposed)
    int f4 = u*256 + tid;
    int r = f4 >> 4, c4 = (f4 & 15) * 4;
    float4 m4 = *(const float4*)(mu + (size_t)f4*4);
    float4 l4 = *(const float4*)(lvu + (size_t)f4*4);
    muT_s[c4+0][r] = m4.x; muT_s[c4+1][r] = m4.y;
    muT_s[c4+2][r] = m4.z; muT_s[c4+3][r] = m4.w;
    ivT_s[c4+0][r] = fminf(fmaxf(l4.x, -6.f), 6.f);
    ivT_s[c4+1][r] = fminf(fmaxf(l4.y, -6.f), 6.f);
    ivT_s[c4+2][r] = fminf(fmaxf(l4.z, -6.f), 6.f);
    ivT_s[c4+3][r] = fminf(fmaxf(l4.w, -6.f), 6.f);
  }
  __syncthreads();
  float ld = 0.f;
  #pragma unroll 8
  for (int d = 0; d < 64; ++d) ld += ivT_s[d][k];   // logdet[k]
  __syncthreads();
  if (w == 0){
    #pragma unroll 8
    for (int d = 0; d < 64; ++d) ivT_s[d][k] = __expf(-ivT_s[d][k]);
  }
  __syncthreads();

  const int t = blockIdx.x * 4 + w;
  float y = Y[(size_t)t*64 + k];
  float quad = 0.f;
  #pragma unroll 8
  for (int d = 0; d < 64; ++d){
    float yd = __shfl(y, d, 64);
    float df = yd - muT_s[d][k];
    quad = fmaf(df*df, ivT_s[d][k], quad);
  }
  float le = -0.5f*(117.6241322f + ld + quad);   // 64*log(2pi)
  float m = le;
  #pragma unroll
  for (int off = 1; off < 64; off <<= 1) m = fmaxf(m, __shfl_xor(m, off, 64));
  emp[(size_t)t*64 + k] = __expf(le - m);
  if (k == 0) cvec[t] = m;

  // X cast: this block's 4 t-rows = 128 float4 (swizzled for linear gld_lds)
  if (tid < 128){
    int rl = tid >> 5, c32 = tid & 31;
    int tr = blockIdx.x*4 + rl;
    float4 v = *(const float4*)(X + (size_t)tr*128 + c32*4);
    int c16 = c32 >> 1, h = c32 & 1;
    int byte = tr*256 + ((c16 ^ (tr & 7))*16 + h*8);
    *(uint2*)((char*)Xsw + byte) = make_uint2(pack2bf(v.x,v.y), pack2bf(v.z,v.w));
  }
  // W cast: blocks 0..511, 256 float4 each
  if (blockIdx.x < 512){
    int f4 = blockIdx.x*256 + tid;
    int r = f4 >> 5, c32 = f4 & 31;    // r = i*64+j
    float4 v = *(const float4*)(W + (size_t)f4*4);
    int c16 = c32 >> 1, h = c32 & 1;
    int byte = r*256 + ((c16 ^ (r & 7))*16 + h*8);
    *(uint2*)((char*)Wsw + byte) = make_uint2(pack2bf(v.x,v.y), pack2bf(v.z,v.w));
  }
}

// ---------------------------------------------------------------- k_trans (MFMA)
// Block (bt, ip): 64 t-rows x 2 source states i. C^T compute (M=j, N=t);
// exp (logits small, no max-sub), j-sum via 2 shfl, normalization in copy-out.
// Copy-out: every store instruction covers 4 rows x 256B fully (no partial
// HBM sectors) — R5 had 2.5x write amplification without this.
__global__ __launch_bounds__(256) void k_trans(
    const u16* __restrict__ Xsw, const u16* __restrict__ Wsw,
    const float* __restrict__ bmat, const float* __restrict__ emp,
    u16* __restrict__ Ap)
{
  __shared__ __align__(16) u16 Wt[128*128];   // 32 KB (2 i-slices, swizzled)
  __shared__ __align__(16) u16 Xt[64*128];    // 16 KB; reused as Ct
  __shared__ float Sred[8][64];               // 2 KB
  const int tid = threadIdx.x;
  const int lane = tid & 63, w = tid >> 6;
  const int lr = lane & 15, lg = lane >> 4;
  const int t0 = blockIdx.x * 64;
  const int i0 = blockIdx.y * 2;

  {
    const char* xsrc = (const char*)(Xsw + (size_t)t0*128);
    const char* wsrc = (const char*)(Wsw + (size_t)i0*64*128);
    #pragma unroll
    for (int c = 0; c < 4; ++c){
      int kb = w*4 + c;
      gld_lds16(xsrc + kb*1024 + lane*16, (char*)Xt + kb*1024);
    }
    #pragma unroll
    for (int c = 0; c < 8; ++c){
      int kb = w*8 + c;
      gld_lds16(wsrc + kb*1024 + lane*16, (char*)Wt + kb*1024);
    }
  }
  __syncthreads();

  f32x4 acc[2][4] = {};
  #pragma unroll
  for (int kg = 0; kg < 4; ++kg){
    const int kc = kg*4 + lg;
    bf16x8 a[2], b[4];
    #pragma unroll
    for (int jt = 0; jt < 2; ++jt){
      int row = (w + jt*4)*16 + lr;     // Wt row = i_local*64 + j
      a[jt] = *(const bf16x8*)((const char*)Wt + row*256 + ((kc ^ (row & 7))*16));
    }
    #pragma unroll
    for (int tt = 0; tt < 4; ++tt){
      int row = tt*16 + lr;             // Xt row = t local
      b[tt] = *(const bf16x8*)((const char*)Xt + row*256 + ((kc ^ (row & 7))*16));
    }
    #pragma unroll
    for (int jt = 0; jt < 2; ++jt)
      #pragma unroll
      for (int tt = 0; tt < 4; ++tt)
        acc[jt][tt] = __builtin_amdgcn_mfma_f32_16x16x32_bf16(a[jt], b[tt], acc[jt][tt], 0, 0, 0);
  }

  float bvv[2][4];
  #pragma unroll
  for (int jt = 0; jt < 2; ++jt){
    int q = w + jt*4;
    int ig = i0 + (q >> 2);
    #pragma unroll
    for (int reg = 0; reg < 4; ++reg)
      bvv[jt][reg] = bmat[ig*64 + (q & 3)*16 + lg*4 + reg];
  }

  __syncthreads();
  u16* Ct = Xt;                         // [64 t][128 j] bf16, row-swizzled

  #pragma unroll
  for (int jt = 0; jt < 2; ++jt){
    const int q = w + jt*4;
    #pragma unroll
    for (int tt = 0; tt < 4; ++tt){
      const int t = tt*16 + lr;
      float e0 = __expf(acc[jt][tt][0] + bvv[jt][0]);
      float e1 = __expf(acc[jt][tt][1] + bvv[jt][1]);
      float e2 = __expf(acc[jt][tt][2] + bvv[jt][2]);
      float e3 = __expf(acc[jt][tt][3] + bvv[jt][3]);
      float s = e0 + e1 + e2 + e3;
      s += __shfl_xor(s, 16, 64);
      s += __shfl_xor(s, 32, 64);
      if (lg == 0) Sred[q][t] = s;
      const int byte = t*256 + ((q*32 + lg*8) ^ ((t & 7) << 4));
      *(u32*)((char*)Ct + byte)     = pack2bf(e0, e1);
      *(u32*)((char*)Ct + byte + 4) = pack2bf(e2, e3);
    }
  }
  __syncthreads();

  { // copy-out: wave w owns rows w*16..w*16+15; per u, 4 rows x 256B full
    const int rl = lane >> 4;           // row in quad
    const int ch = lane & 15;           // 16B chunk in 256B row
    const int h = ch >> 3;              // i-half
    #pragma unroll
    for (int u = 0; u < 4; ++u){
      const int row = w*16 + u*4 + rl;
      float s = Sred[h*4+0][row] + Sred[h*4+1][row]
              + Sred[h*4+2][row] + Sred[h*4+3][row];
      const float inv = 1.0f / s;
      uint4 v = *(const uint4*)((const char*)Ct + row*256 + ((ch*16) ^ ((row & 7) << 4)));
      const float* er = emp + (size_t)(t0 + row)*64 + (ch & 7)*8;
      float4 ea = *(const float4*)(er);
      float4 eb = *(const float4*)(er + 4);
      u32 r0 = pack2bf(bflo(v.x)*inv*ea.x, bfhi(v.x)*inv*ea.y);
      u32 r1 = pack2bf(bflo(v.y)*inv*ea.z, bfhi(v.y)*inv*ea.w);
      u32 r2 = pack2bf(bflo(v.z)*inv*eb.x, bfhi(v.z)*inv*eb.y);
      u32 r3 = pack2bf(bflo(v.w)*inv*eb.z, bfhi(v.w)*inv*eb.w);
      *(uint4*)(Ap + (size_t)(t0 + row)*4096 + (size_t)i0*64 + ch*8) = make_uint4(r0, r1, r2, r3);
    }
  }
}

// ---------------------------------------------------------------- fold_chunk
// Fold cnt matrices (slot c*mstride, 4096 elems each) into one, in place at
// slot c0_in*mstride. Transposed-space MFMA (verified R4-R6).
__device__ void fold_chunk(
    u16* mats, int c0_in, int mstride, int cnt_in, int skip,
    const float* in_sc, float* out_sc, int tid, u32 (&Apk)[2][32*68])
{
  const int lane = tid & 63, w = tid >> 6;
  const int r16 = lane & 15, oct = lane >> 4;
  int c0 = c0_in + skip, cnt = cnt_in - skip;
  const size_t out_slot = (size_t)c0_in * mstride;

  bf16x8 Bf[2];
  {
    const u16* m0 = mats + ((size_t)c0*mstride << 12) + (w*16 + r16)*64 + oct*8;
    Bf[0] = *(const bf16x8*)(m0);
    Bf[1] = *(const bf16x8*)(m0 + 32);
  }
  float S = in_sc ? in_sc[c0*4 + w] : 0.0f;

  const int lp = tid >> 3, c8 = tid & 7;
  auto STAGE = [&](int buf, const u16* src){
    const uint4 A = *(const uint4*)(src + lp*128 + c8*8);
    const uint4 B = *(const uint4*)(src + lp*128 + 64 + c8*8);
    uint4 o0, o1;
    o0.x = (A.x & 0xffffu) | (B.x << 16);
    o0.y = (A.x >> 16)     | (B.x & 0xffff0000u);
    o0.z = (A.y & 0xffffu) | (B.y << 16);
    o0.w = (A.y >> 16)     | (B.y & 0xffff0000u);
    o1.x = (A.z & 0xffffu) | (B.z << 16);
    o1.y = (A.z >> 16)     | (B.z & 0xffff0000u);
    o1.z = (A.w & 0xffffu) | (B.w << 16);
    o1.w = (A.w >> 16)     | (B.w & 0xffff0000u);
    u32* dst = &Apk[buf][lp*68 + c8*8];
    *(uint4*)(dst)     = o0;
    *(uint4*)(dst + 4) = o1;
  };

  if (cnt > 1) STAGE(0, mats + ((size_t)(c0+1)*mstride << 12));
  __syncthreads();
  int cur = 0;
  for (int kk = 1; kk < cnt; ++kk){
    if (kk + 1 < cnt) STAGE(cur ^ 1, mats + ((size_t)(c0 + kk + 1)*mstride << 12));

    if (in_sc){
      const float* sp = in_sc + (size_t)(c0 + kk)*4;
      float s0=sp[0], s1=sp[1], s2=sp[2], s3=sp[3];
      float sm = fmaxf(fmaxf(s0,s1), fmaxf(s2,s3));
      S += sm;
      #pragma unroll
      for (int kt = 0; kt < 2; ++kt){
        float slo = (kt == 0) ? s0 : s2;
        float shi = (kt == 0) ? s1 : s3;
        float se = __expf(((oct >> 1) ? shi : slo) - sm);
        uint4 bv4 = __builtin_bit_cast(uint4, Bf[kt]);
        bv4.x = pack2bf(bflo(bv4.x)*se, bfhi(bv4.x)*se);
        bv4.y = pack2bf(bflo(bv4.y)*se, bfhi(bv4.y)*se);
        bv4.z = pack2bf(bflo(bv4.z)*se, bfhi(bv4.z)*se);
        bv4.w = pack2bf(bflo(bv4.w)*se, bfhi(bv4.w)*se);
        Bf[kt] = __builtin_bit_cast(bf16x8, bv4);
      }
    }

    f32x4 acc[4] = {};
    const u32* Ab = &Apk[cur][0];
    #pragma unroll
    for (int kt = 0; kt < 2; ++kt){
      const u32* gb = Ab + (kt*16 + oct*4)*68 + r16;
      #pragma unroll
      for (int jt = 0; jt < 4; ++jt){
        const u32* g = gb + jt*16;
        uint4 av = make_uint4(g[0], g[68], g[136], g[204]);
        acc[jt] = __builtin_amdgcn_mfma_f32_16x16x32_bf16(
            __builtin_bit_cast(bf16x8, av), Bf[kt], acc[jt], 0, 0, 0);
      }
    }

    float mx = acc[0][0];
    #pragma unroll
    for (int jt = 0; jt < 4; ++jt)
      #pragma unroll
      for (int q = 0; q < 4; ++q) mx = fmaxf(mx, acc[jt][q]);
    #pragma unroll
    for (int off = 1; off < 64; off <<= 1) mx = fmaxf(mx, __shfl_xor(mx, off, 64));
    float inv = 1.0f / mx;
    S += __logf(mx);

    u32 p0[4], p1[4];
    #pragma unroll
    for (int jt = 0; jt < 4; ++jt){
      p0[jt] = pack2bf(acc[jt][0]*inv, acc[jt][1]*inv);
      p1[jt] = pack2bf(acc[jt][2]*inv, acc[jt][3]*inv);
    }
    const int s0l = r16 + 32*(oct & 1), s1l = s0l + 16;
    const bool hi = (oct >> 1) != 0;
    #pragma unroll
    for (int kt = 0; kt < 2; ++kt){
      u32 a0 = __shfl(p0[2*kt],   s0l, 64), a1 = __shfl(p1[2*kt],   s0l, 64);
      u32 a2 = __shfl(p0[2*kt],   s1l, 64), a3 = __shfl(p1[2*kt],   s1l, 64);
      u32 b0 = __shfl(p0[2*kt+1], s0l, 64), b1 = __shfl(p1[2*kt+1], s0l, 64);
      u32 b2 = __shfl(p0[2*kt+1], s1l, 64), b3 = __shfl(p1[2*kt+1], s1l, 64);
      uint4 nb;
      nb.x = hi ? b0 : a0;
      nb.y = hi ? b1 : a1;
      nb.z = hi ? b2 : a2;
      nb.w = hi ? b3 : a3;
      Bf[kt] = __builtin_bit_cast(bf16x8, nb);
    }
    cur ^= 1;
    __syncthreads();
  }
  {
    u16* outp = mats + (out_slot << 12) + (w*16 + r16)*64 + oct*8;
    *(bf16x8*)(outp)      = Bf[0];
    *(bf16x8*)(outp + 32) = Bf[1];
    if (lane == 0) out_sc[w] = S;
  }
}

// ---------------------------------------------------------------- final_ll
__device__ void final_ll(
    const float* init_logits, const float* emp, const float* cvec,
    const u16* Mfin, const float* scfin, float* out, int tid)
{
  __shared__ float wsum[4];
  float part = 0.f;
  for (int t = tid; t < T_LEN; t += 256) part += cvec[t];
  #pragma unroll
  for (int off = 1; off < 64; off <<= 1) part += __shfl_xor(part, off, 64);
  if ((tid & 63) == 0) wsum[tid >> 6] = part;
  __syncthreads();
  if (tid >= 64) return;
  const float csum = wsum[0] + wsum[1] + wsum[2] + wsum[3];
  const int k = tid;
  float ilv = init_logits[k];
  float m = ilv;
  #pragma unroll
  for (int off = 1; off < 64; off <<= 1) m = fmaxf(m, __shfl_xor(m, off, 64));
  float e = __expf(ilv - m);
  float s = e;
  #pragma unroll
  for (int off = 1; off < 64; off <<= 1) s += __shfl_xor(s, off, 64);
  float alpha = (e / s) * emp[k];
  float sm = fmaxf(fmaxf(scfin[0], scfin[1]), fmaxf(scfin[2], scfin[3]));
  alpha *= __expf(scfin[k >> 4] - sm);
  float S = sm;
  float an = 0.f;
  for (int i2 = 0; i2 < 64; ++i2){
    float av = __shfl(alpha, i2, 64);
    an = fmaf(av, __uint_as_float(((u32)Mfin[i2*64 + k]) << 16), an);
  }
  float tot = an;
  #pragma unroll
  for (int off = 1; off < 64; off <<= 1) tot += __shfl_xor(tot, off, 64);
  if (k == 0) out[0] = __logf(tot) + S + csum;
}

// ---------------------------------------------------------------- k_scan_lvl
__global__ __launch_bounds__(256) void k_scan_lvl(
    u16* mats, int mstride, int per_wg, int skip0,
    const float* __restrict__ in_sc, float* __restrict__ out_sc)
{
  __shared__ u32 Apk[2][32*68];
  const int b = blockIdx.x;
  fold_chunk(mats, b*per_wg, mstride, per_wg, (b == 0) ? skip0 : 0,
             in_sc, out_sc + b*4, threadIdx.x, Apk);
}

// ---------------------------------------------------------------- k_tail
// single block: fold 16 chunk-matrices (stride 512) -> slot 0, then final ll.
__global__ __launch_bounds__(256) void k_tail(
    u16* mats, const float* __restrict__ in_sc,
    const float* __restrict__ init_logits, const float* __restrict__ emp,
    const float* __restrict__ cvec, float* __restrict__ out)
{
  __shared__ u32 Apk[2][32*68];
  __shared__ float scf[4];
  const int tid = threadIdx.x;
  fold_chunk(mats, 0, 512, 16, 0, in_sc, scf, tid, Apk);
  __syncthreads();
  final_ll(init_logits, emp, cvec, mats, scf, out, tid);
}

// ---------------------------------------------------------------- launch
extern "C" void kernel_launch(void* const* d_in, const int* in_sizes, int n_in,
                              void* d_out, int out_size, void* d_ws, size_t ws_size,
                              hipStream_t stream)
{
  const float* X  = (const float*)d_in[0];
  const float* Y  = (const float*)d_in[1];
  const float* il = (const float*)d_in[2];
  const float* W  = (const float*)d_in[3];
  const float* bm = (const float*)d_in[4];
  const float* mu = (const float*)d_in[5];
  const float* lv = (const float*)d_in[6];
  float* out = (float*)d_out;
  char* ws = (char*)d_ws;
  (void)in_sizes; (void)n_in; (void)out_size; (void)ws_size; // need ~73.5 MB ws

  float* emp  = (float*)(ws + 0x0000000);
  float* cvec = (float*)(ws + 0x0200000);
  float* sc1  = (float*)(ws + 0x0220000);
  float* sc2  = (float*)(ws + 0x0224000);
  float* sc3  = (float*)(ws + 0x0225000);
  u16*   Xsw  = (u16*)  (ws + 0x0240000);
  u16*   Wsw  = (u16*)  (ws + 0x0440000);
  u16*   Ap   = (u16*)  (ws + 0x0600000);

  k_emis <<<2048, 256, 0, stream>>>(Y, mu, lv, X, W, emp, cvec, Xsw, Wsw);
  k_trans<<<dim3(128, 32), 256, 0, stream>>>(Xsw, Wsw, bm, emp, Ap);
  k_scan_lvl<<<1024, 256, 0, stream>>>(Ap,  1, 8, 1, (const float*)nullptr, sc1);
  k_scan_lvl<<<128,  256, 0, stream>>>(Ap,  8, 8, 0, sc1, sc2);
  k_scan_lvl<<<16,   256, 0, stream>>>(Ap, 64, 8, 0, sc2, sc3);
  k_tail<<<1, 256, 0, stream>>>(Ap, sc3, il, emp, cvec, out);
}

// Round 9
// 190.295 us; speedup vs baseline: 3.3226x; 1.0042x over previous
//
#include <hip/hip_runtime.h>
#include <hip/hip_bf16.h>

// TVHMM forward log-likelihood, chunk-parallel linear-domain operator scan.
// R8 (resubmit after GPU acquisition timeout): prefetch-ALL fold —
//     fold_chunk stages up to NBUF operand matrices into LDS up front (one
//     barrier), then folds with no barriers / no global reads in the loop.
//     Kills the latency-bound serial chains in the scan tail (L1/L2/k_tail
//     were ~1-2us per dependent 8KB load round-trip).
// 6 launches: k_emis(+prep), k_trans, L0 1024x8, L1 128x8, L2 16x8,
//     k_tail (fold16->1 + final ll, NBUF=15).
// ws layout (bytes), ~73.5 MB total:
//   0x0000000 emp[8192][64] f32   0x0200000 cvec[8192] f32
//   0x0220000 sc1[1024][4]  0x0224000 sc2[128][4]  0x0225000 sc3[16][4]
//   0x0240000 Xsw[8192][128] bf16 pre-swizzled (2 MB)
//   0x0440000 Wsw[64*64][128] bf16 pre-swizzled (1 MB)
//   0x0600000 Ap[8192][64][64] bf16 (64 MB), scan tree folds in place
// NOTE (R6 lesson): grid.sync costs ~125us/sync at 1024 blocks — never again.
// NOTE (R7 lesson): harness re-poison of 256MiB ws = fixed ~45us fill on the
//     stream before our first kernel; it is part of measured dur_us.

typedef unsigned int u32;
typedef unsigned short u16;

#define T_LEN 8192

typedef __attribute__((ext_vector_type(8))) short bf16x8;
typedef __attribute__((ext_vector_type(4))) float f32x4;

__device__ __forceinline__ float bflo(u32 u){ return __uint_as_float(u << 16); }
__device__ __forceinline__ float bfhi(u32 u){ return __uint_as_float(u & 0xffff0000u); }
__device__ __forceinline__ u32 f2bf(float x){
  u32 b = __float_as_uint(x);
  return (b + 0x7fffu + ((b >> 16) & 1u)) >> 16;
}
__device__ __forceinline__ u32 pack2bf(float a, float b){
  return f2bf(a) | (f2bf(b) << 16);
}

__device__ __forceinline__ void gld_lds16(const void* g, void* l){
#if defined(__has_builtin) && __has_builtin(__builtin_amdgcn_global_load_lds)
  __builtin_amdgcn_global_load_lds(
      (const __attribute__((address_space(1))) unsigned int*)g,
      (__attribute__((address_space(3))) unsigned int*)l, 16, 0, 0);
#else
  *(uint4*)((char*)l + (threadIdx.x & 63) * 16) = *(const uint4*)g;
#endif
}

// ---------------------------------------------------------------- k_emis
// emissions (mu / exp(-lv) staged in padded LDS; logdet per lane) + fused
// f32->bf16 pre-swizzled casts of X and W for k_trans's global_load_lds.
__global__ __launch_bounds__(256) void k_emis(
    const float* __restrict__ Y, const float* __restrict__ mu,
    const float* __restrict__ lvu,
    const float* __restrict__ X, const float* __restrict__ W,
    float* __restrict__ emp, float* __restrict__ cvec,
    u16* __restrict__ Xsw, u16* __restrict__ Wsw)
{
  __shared__ float muT_s[64][65];   // [d][k], +1 pad
  __shared__ float ivT_s[64][65];   // lv then exp(-lv)
  const int tid = threadIdx.x;
  const int w = tid >> 6, k = tid & 63;

  #pragma unroll
  for (int u = 0; u < 4; ++u){      // stage mu, clipped lv (transposed)
    int f4 = u*256 + tid;
    int r = f4 >> 4, c4 = (f4 & 15) * 4;
    float4 m4 = *(const float4*)(mu + (size_t)f4*4);
    float4 l4 = *(const float4*)(lvu + (size_t)f4*4);
    muT_s[c4+0][r] = m4.x; muT_s[c4+1][r] = m4.y;
    muT_s[c4+2][r] = m4.z; muT_s[c4+3][r] = m4.w;
    ivT_s[c4+0][r] = fminf(fmaxf(l4.x, -6.f), 6.f);
    ivT_s[c4+1][r] = fminf(fmaxf(l4.y, -6.f), 6.f);
    ivT_s[c4+2][r] = fminf(fmaxf(l4.z, -6.f), 6.f);
    ivT_s[c4+3][r] = fminf(fmaxf(l4.w, -6.f), 6.f);
  }
  __syncthreads();
  float ld = 0.f;
  #pragma unroll 8
  for (int d = 0; d < 64; ++d) ld += ivT_s[d][k];   // logdet[k]
  __syncthreads();
  if (w == 0){
    #pragma unroll 8
    for (int d = 0; d < 64; ++d) ivT_s[d][k] = __expf(-ivT_s[d][k]);
  }
  __syncthreads();

  const int t = blockIdx.x * 4 + w;
  float y = Y[(size_t)t*64 + k];
  float quad = 0.f;
  #pragma unroll 8
  for (int d = 0; d < 64; ++d){
    float yd = __shfl(y, d, 64);
    float df = yd - muT_s[d][k];
    quad = fmaf(df*df, ivT_s[d][k], quad);
  }
  float le = -0.5f*(117.6241322f + ld + quad);   // 64*log(2pi)
  float m = le;
  #pragma unroll
  for (int off = 1; off < 64; off <<= 1) m = fmaxf(m, __shfl_xor(m, off, 64));
  emp[(size_t)t*64 + k] = __expf(le - m);
  if (k == 0) cvec[t] = m;

  // X cast: this block's 4 t-rows = 128 float4 (swizzled for linear gld_lds)
  if (tid < 128){
    int rl = tid >> 5, c32 = tid & 31;
    int tr = blockIdx.x*4 + rl;
    float4 v = *(const float4*)(X + (size_t)tr*128 + c32*4);
    int c16 = c32 >> 1, h = c32 & 1;
    int byte = tr*256 + ((c16 ^ (tr & 7))*16 + h*8);
    *(uint2*)((char*)Xsw + byte) = make_uint2(pack2bf(v.x,v.y), pack2bf(v.z,v.w));
  }
  // W cast: blocks 0..511, 256 float4 each
  if (blockIdx.x < 512){
    int f4 = blockIdx.x*256 + tid;
    int r = f4 >> 5, c32 = f4 & 31;    // r = i*64+j
    float4 v = *(const float4*)(W + (size_t)f4*4);
    int c16 = c32 >> 1, h = c32 & 1;
    int byte = r*256 + ((c16 ^ (r & 7))*16 + h*8);
    *(uint2*)((char*)Wsw + byte) = make_uint2(pack2bf(v.x,v.y), pack2bf(v.z,v.w));
  }
}

// ---------------------------------------------------------------- k_trans (MFMA)
// Block (bt, ip): 64 t-rows x 2 source states i. C^T compute (M=j, N=t);
// exp (logits small, no max-sub), j-sum via 2 shfl, normalization in copy-out.
// Copy-out: every store instruction covers 4 rows x 256B fully (no partial
// HBM sectors) — R5 had 2.5x write amplification without this.
__global__ __launch_bounds__(256) void k_trans(
    const u16* __restrict__ Xsw, const u16* __restrict__ Wsw,
    const float* __restrict__ bmat, const float* __restrict__ emp,
    u16* __restrict__ Ap)
{
  __shared__ __align__(16) u16 Wt[128*128];   // 32 KB (2 i-slices, swizzled)
  __shared__ __align__(16) u16 Xt[64*128];    // 16 KB; reused as Ct
  __shared__ float Sred[8][64];               // 2 KB
  const int tid = threadIdx.x;
  const int lane = tid & 63, w = tid >> 6;
  const int lr = lane & 15, lg = lane >> 4;
  const int t0 = blockIdx.x * 64;
  const int i0 = blockIdx.y * 2;

  {
    const char* xsrc = (const char*)(Xsw + (size_t)t0*128);
    const char* wsrc = (const char*)(Wsw + (size_t)i0*64*128);
    #pragma unroll
    for (int c = 0; c < 4; ++c){
      int kb = w*4 + c;
      gld_lds16(xsrc + kb*1024 + lane*16, (char*)Xt + kb*1024);
    }
    #pragma unroll
    for (int c = 0; c < 8; ++c){
      int kb = w*8 + c;
      gld_lds16(wsrc + kb*1024 + lane*16, (char*)Wt + kb*1024);
    }
  }
  __syncthreads();

  f32x4 acc[2][4] = {};
  #pragma unroll
  for (int kg = 0; kg < 4; ++kg){
    const int kc = kg*4 + lg;
    bf16x8 a[2], b[4];
    #pragma unroll
    for (int jt = 0; jt < 2; ++jt){
      int row = (w + jt*4)*16 + lr;     // Wt row = i_local*64 + j
      a[jt] = *(const bf16x8*)((const char*)Wt + row*256 + ((kc ^ (row & 7))*16));
    }
    #pragma unroll
    for (int tt = 0; tt < 4; ++tt){
      int row = tt*16 + lr;             // Xt row = t local
      b[tt] = *(const bf16x8*)((const char*)Xt + row*256 + ((kc ^ (row & 7))*16));
    }
    #pragma unroll
    for (int jt = 0; jt < 2; ++jt)
      #pragma unroll
      for (int tt = 0; tt < 4; ++tt)
        acc[jt][tt] = __builtin_amdgcn_mfma_f32_16x16x32_bf16(a[jt], b[tt], acc[jt][tt], 0, 0, 0);
  }

  float bvv[2][4];
  #pragma unroll
  for (int jt = 0; jt < 2; ++jt){
    int q = w + jt*4;
    int ig = i0 + (q >> 2);
    #pragma unroll
    for (int reg = 0; reg < 4; ++reg)
      bvv[jt][reg] = bmat[ig*64 + (q & 3)*16 + lg*4 + reg];
  }

  __syncthreads();
  u16* Ct = Xt;                         // [64 t][128 j] bf16, row-swizzled

  #pragma unroll
  for (int jt = 0; jt < 2; ++jt){
    const int q = w + jt*4;
    #pragma unroll
    for (int tt = 0; tt < 4; ++tt){
      const int t = tt*16 + lr;
      float e0 = __expf(acc[jt][tt][0] + bvv[jt][0]);
      float e1 = __expf(acc[jt][tt][1] + bvv[jt][1]);
      float e2 = __expf(acc[jt][tt][2] + bvv[jt][2]);
      float e3 = __expf(acc[jt][tt][3] + bvv[jt][3]);
      float s = e0 + e1 + e2 + e3;
      s += __shfl_xor(s, 16, 64);
      s += __shfl_xor(s, 32, 64);
      if (lg == 0) Sred[q][t] = s;
      const int byte = t*256 + ((q*32 + lg*8) ^ ((t & 7) << 4));
      *(u32*)((char*)Ct + byte)     = pack2bf(e0, e1);
      *(u32*)((char*)Ct + byte + 4) = pack2bf(e2, e3);
    }
  }
  __syncthreads();

  { // copy-out: wave w owns rows w*16..w*16+15; per u, 4 rows x 256B full
    const int rl = lane >> 4;           // row in quad
    const int ch = lane & 15;           // 16B chunk in 256B row
    const int h = ch >> 3;              // i-half
    #pragma unroll
    for (int u = 0; u < 4; ++u){
      const int row = w*16 + u*4 + rl;
      float s = Sred[h*4+0][row] + Sred[h*4+1][row]
              + Sred[h*4+2][row] + Sred[h*4+3][row];
      const float inv = 1.0f / s;
      uint4 v = *(const uint4*)((const char*)Ct + row*256 + ((ch*16) ^ ((row & 7) << 4)));
      const float* er = emp + (size_t)(t0 + row)*64 + (ch & 7)*8;
      float4 ea = *(const float4*)(er);
      float4 eb = *(const float4*)(er + 4);
      u32 r0 = pack2bf(bflo(v.x)*inv*ea.x, bfhi(v.x)*inv*ea.y);
      u32 r1 = pack2bf(bflo(v.y)*inv*ea.z, bfhi(v.y)*inv*ea.w);
      u32 r2 = pack2bf(bflo(v.z)*inv*eb.x, bfhi(v.z)*inv*eb.y);
      u32 r3 = pack2bf(bflo(v.w)*inv*eb.z, bfhi(v.w)*inv*eb.w);
      *(uint4*)(Ap + (size_t)(t0 + row)*4096 + (size_t)i0*64 + ch*8) = make_uint4(r0, r1, r2, r3);
    }
  }
}

// ---------------------------------------------------------------- fold_chunk
// Fold cnt matrices (slot c*mstride, 4096 elems each) into one, in place at
// slot c0_in*mstride. Transposed-space MFMA (verified R4-R7).
// R8: group-prefetch — stage up to NBUF operand mats into LDS (loads issued
// back-to-back, ONE barrier), then fold with no barriers / no global reads.
template<int NBUF>
__device__ void fold_chunk(
    u16* mats, int c0_in, int mstride, int cnt_in, int skip,
    const float* in_sc, float* out_sc, int tid, u32 (*Apk)[2176])
{
  const int lane = tid & 63, w = tid >> 6;
  const int r16 = lane & 15, oct = lane >> 4;
  int c0 = c0_in + skip, cnt = cnt_in - skip;
  const size_t out_slot = (size_t)c0_in * mstride;

  bf16x8 Bf[2];
  {
    const u16* m0 = mats + ((size_t)c0*mstride << 12) + (w*16 + r16)*64 + oct*8;
    Bf[0] = *(const bf16x8*)(m0);
    Bf[1] = *(const bf16x8*)(m0 + 32);
  }
  float S = in_sc ? in_sc[c0*4 + w] : 0.0f;

  const int lp = tid >> 3, c8 = tid & 7;
  auto STAGE = [&](int buf, const u16* src){
    const uint4 A = *(const uint4*)(src + lp*128 + c8*8);
    const uint4 B = *(const uint4*)(src + lp*128 + 64 + c8*8);
    uint4 o0, o1;
    o0.x = (A.x & 0xffffu) | (B.x << 16);
    o0.y = (A.x >> 16)     | (B.x & 0xffff0000u);
    o0.z = (A.y & 0xffffu) | (B.y << 16);
    o0.w = (A.y >> 16)     | (B.y & 0xffff0000u);
    o1.x = (A.z & 0xffffu) | (B.z << 16);
    o1.y = (A.z >> 16)     | (B.z & 0xffff0000u);
    o1.z = (A.w & 0xffffu) | (B.w << 16);
    o1.w = (A.w >> 16)     | (B.w & 0xffff0000u);
    u32* dst = &Apk[buf][lp*68 + c8*8];
    *(uint4*)(dst)     = o0;
    *(uint4*)(dst + 4) = o1;
  };

  for (int g0 = 1; g0 < cnt; g0 += NBUF){
    const int ge = (g0 + NBUF < cnt) ? (g0 + NBUF) : cnt;
    if (g0 > 1) __syncthreads();           // protect buffer reuse across groups
    for (int kk = g0; kk < ge; ++kk)
      STAGE(kk - g0, mats + ((size_t)(c0 + kk)*mstride << 12));
    __syncthreads();

    for (int kk = g0; kk < ge; ++kk){
      if (in_sc){ // fold Op's row-block scales into state columns (i-blocks)
        const float* sp = in_sc + (size_t)(c0 + kk)*4;
        float s0=sp[0], s1=sp[1], s2=sp[2], s3=sp[3];
        float sm = fmaxf(fmaxf(s0,s1), fmaxf(s2,s3));
        S += sm;
        #pragma unroll
        for (int kt = 0; kt < 2; ++kt){
          float slo = (kt == 0) ? s0 : s2;
          float shi = (kt == 0) ? s1 : s3;
          float se = __expf(((oct >> 1) ? shi : slo) - sm);
          uint4 bv4 = __builtin_bit_cast(uint4, Bf[kt]);
          bv4.x = pack2bf(bflo(bv4.x)*se, bfhi(bv4.x)*se);
          bv4.y = pack2bf(bflo(bv4.y)*se, bfhi(bv4.y)*se);
          bv4.z = pack2bf(bflo(bv4.z)*se, bfhi(bv4.z)*se);
          bv4.w = pack2bf(bflo(bv4.w)*se, bfhi(bv4.w)*se);
          Bf[kt] = __builtin_bit_cast(bf16x8, bv4);
        }
      }

      f32x4 acc[4] = {};
      const u32* Ab = Apk[kk - g0];
      #pragma unroll
      for (int kt = 0; kt < 2; ++kt){
        const u32* gb = Ab + (kt*16 + oct*4)*68 + r16;
        #pragma unroll
        for (int jt = 0; jt < 4; ++jt){
          const u32* g = gb + jt*16;
          uint4 av = make_uint4(g[0], g[68], g[136], g[204]);
          acc[jt] = __builtin_amdgcn_mfma_f32_16x16x32_bf16(
              __builtin_bit_cast(bf16x8, av), Bf[kt], acc[jt], 0, 0, 0);
        }
      }

      float mx = acc[0][0];
      #pragma unroll
      for (int jt = 0; jt < 4; ++jt)
        #pragma unroll
        for (int q = 0; q < 4; ++q) mx = fmaxf(mx, acc[jt][q]);
      #pragma unroll
      for (int off = 1; off < 64; off <<= 1) mx = fmaxf(mx, __shfl_xor(mx, off, 64));
      float inv = 1.0f / mx;
      S += __logf(mx);

      u32 p0[4], p1[4];
      #pragma unroll
      for (int jt = 0; jt < 4; ++jt){
        p0[jt] = pack2bf(acc[jt][0]*inv, acc[jt][1]*inv);
        p1[jt] = pack2bf(acc[jt][2]*inv, acc[jt][3]*inv);
      }
      const int s0l = r16 + 32*(oct & 1), s1l = s0l + 16;
      const bool hi = (oct >> 1) != 0;
      #pragma unroll
      for (int kt = 0; kt < 2; ++kt){
        u32 a0 = __shfl(p0[2*kt],   s0l, 64), a1 = __shfl(p1[2*kt],   s0l, 64);
        u32 a2 = __shfl(p0[2*kt],   s1l, 64), a3 = __shfl(p1[2*kt],   s1l, 64);
        u32 b0 = __shfl(p0[2*kt+1], s0l, 64), b1 = __shfl(p1[2*kt+1], s0l, 64);
        u32 b2 = __shfl(p0[2*kt+1], s1l, 64), b3 = __shfl(p1[2*kt+1], s1l, 64);
        uint4 nb;
        nb.x = hi ? b0 : a0;
        nb.y = hi ? b1 : a1;
        nb.z = hi ? b2 : a2;
        nb.w = hi ? b3 : a3;
        Bf[kt] = __builtin_bit_cast(bf16x8, nb);
      }
    }
  }
  {
    u16* outp = mats + (out_slot << 12) + (w*16 + r16)*64 + oct*8;
    *(bf16x8*)(outp)      = Bf[0];
    *(bf16x8*)(outp + 32) = Bf[1];
    if (lane == 0) out_sc[w] = S;
  }
}

// ---------------------------------------------------------------- final_ll
__device__ void final_ll(
    const float* init_logits, const float* emp, const float* cvec,
    const u16* Mfin, const float* scfin, float* out, int tid)
{
  __shared__ float wsum[4];
  float part = 0.f;
  for (int t = tid; t < T_LEN; t += 256) part += cvec[t];
  #pragma unroll
  for (int off = 1; off < 64; off <<= 1) part += __shfl_xor(part, off, 64);
  if ((tid & 63) == 0) wsum[tid >> 6] = part;
  __syncthreads();
  if (tid >= 64) return;
  const float csum = wsum[0] + wsum[1] + wsum[2] + wsum[3];
  const int k = tid;
  float ilv = init_logits[k];
  float m = ilv;
  #pragma unroll
  for (int off = 1; off < 64; off <<= 1) m = fmaxf(m, __shfl_xor(m, off, 64));
  float e = __expf(ilv - m);
  float s = e;
  #pragma unroll
  for (int off = 1; off < 64; off <<= 1) s += __shfl_xor(s, off, 64);
  float alpha = (e / s) * emp[k];
  float sm = fmaxf(fmaxf(scfin[0], scfin[1]), fmaxf(scfin[2], scfin[3]));
  alpha *= __expf(scfin[k >> 4] - sm);
  float S = sm;
  float an = 0.f;
  for (int i2 = 0; i2 < 64; ++i2){
    float av = __shfl(alpha, i2, 64);
    an = fmaf(av, __uint_as_float(((u32)Mfin[i2*64 + k]) << 16), an);
  }
  float tot = an;
  #pragma unroll
  for (int off = 1; off < 64; off <<= 1) tot += __shfl_xor(tot, off, 64);
  if (k == 0) out[0] = __logf(tot) + S + csum;
}

// ---------------------------------------------------------------- k_scan_lvl
__global__ __launch_bounds__(256) void k_scan_lvl(
    u16* mats, int mstride, int per_wg, int skip0,
    const float* __restrict__ in_sc, float* __restrict__ out_sc)
{
  __shared__ u32 Apk[7][2176];   // 61 KB: prefetch-all for fold-8 levels
  const int b = blockIdx.x;
  fold_chunk<7>(mats, b*per_wg, mstride, per_wg, (b == 0) ? skip0 : 0,
                in_sc, out_sc + b*4, threadIdx.x, Apk);
}

// ---------------------------------------------------------------- k_tail
// single block: fold 16 chunk-matrices (stride 512) -> slot 0, then final ll.
__global__ __launch_bounds__(256) void k_tail(
    u16* mats, const float* __restrict__ in_sc,
    const float* __restrict__ init_logits, const float* __restrict__ emp,
    const float* __restrict__ cvec, float* __restrict__ out)
{
  __shared__ u32 Apk[15][2176];  // 131 KB: all 15 operands staged at once
  __shared__ float scf[4];
  const int tid = threadIdx.x;
  fold_chunk<15>(mats, 0, 512, 16, 0, in_sc, scf, tid, Apk);
  __syncthreads();
  final_ll(init_logits, emp, cvec, mats, scf, out, tid);
}

// ---------------------------------------------------------------- launch
extern "C" void kernel_launch(void* const* d_in, const int* in_sizes, int n_in,
                              void* d_out, int out_size, void* d_ws, size_t ws_size,
                              hipStream_t stream)
{
  const float* X  = (const float*)d_in[0];
  const float* Y  = (const float*)d_in[1];
  const float* il = (const float*)d_in[2];
  const float* W  = (const float*)d_in[3];
  const float* bm = (const float*)d_in[4];
  const float* mu = (const float*)d_in[5];
  const float* lv = (const float*)d_in[6];
  float* out = (float*)d_out;
  char* ws = (char*)d_ws;
  (void)in_sizes; (void)n_in; (void)out_size; (void)ws_size; // need ~73.5 MB ws

  float* emp  = (float*)(ws + 0x0000000);
  float* cvec = (float*)(ws + 0x0200000);
  float* sc1  = (float*)(ws + 0x0220000);
  float* sc2  = (float*)(ws + 0x0224000);
  float* sc3  = (float*)(ws + 0x0225000);
  u16*   Xsw  = (u16*)  (ws + 0x0240000);
  u16*   Wsw  = (u16*)  (ws + 0x0440000);
  u16*   Ap   = (u16*)  (ws + 0x0600000);

  k_emis <<<2048, 256, 0, stream>>>(Y, mu, lv, X, W, emp, cvec, Xsw, Wsw);
  k_trans<<<dim3(128, 32), 256, 0, stream>>>(Xsw, Wsw, bm, emp, Ap);
  k_scan_lvl<<<1024, 256, 0, stream>>>(Ap,  1, 8, 1, (const float*)nullptr, sc1);
  k_scan_lvl<<<128,  256, 0, stream>>>(Ap,  8, 8, 0, sc1, sc2);
  k_scan_lvl<<<16,   256, 0, stream>>>(Ap, 64, 8, 0, sc2, sc3);
  k_tail<<<1, 256, 0, stream>>>(Ap, sc3, il, emp, cvec, out);
}